// Round 1
// baseline (673.635 us; speedup 1.0000x reference)
//
#include <hip/hip_runtime.h>

#define EPS 1e-7f
#define CCH 42
#define NCON 8

// ---------------------------------------------------------------------------
// Kernel 1: tau_total reduction + transmission exps.
// Thread i <-> (n = i/42, c = i%42); tau flat layout makes tau[n,c,:] = tau[8i..8i+7].
// Fully coalesced float4 reads and float stores.
// ---------------------------------------------------------------------------
__global__ __launch_bounds__(256) void k_trans(
    const float* __restrict__ tau,
    const float* __restrict__ mu_direct,
    const float* __restrict__ mu_diffuse,
    float* __restrict__ out, int total, size_t nctot)
{
    int i = blockIdx.x * 256 + threadIdx.x;
    if (i >= total) return;
    const float4* t4 = (const float4*)tau + (size_t)i * 2;
    float4 a = t4[0];
    float4 b = t4[1];
    float s = ((a.x + a.y) + (a.z + a.w)) + ((b.x + b.y) + (b.z + b.w));
    int n = i / CCH;
    float md = mu_direct[n] + EPS;
    float mf = mu_diffuse[n] + EPS;
    out[i] = __expf(-s / md);
    out[nctot + i] = __expf(-s / mf);
}

// ---------------------------------------------------------------------------
// Per-channel MLP (dims NIN -> 5 -> 4 -> 4 -> 3) + 3-way softmax.
// `c` is wave-uniform (forced through readfirstlane by the caller), so all
// weight/bias loads should compile to s_load and FMAs use SGPR operands.
// ---------------------------------------------------------------------------
template<int NIN>
__device__ __forceinline__ void mlp_softmax3(
    const float x[NIN], int c,
    const float* __restrict__ W0, const float* __restrict__ b0,
    const float* __restrict__ W1, const float* __restrict__ b1,
    const float* __restrict__ W2, const float* __restrict__ b2,
    const float* __restrict__ W3, const float* __restrict__ b3,
    float o[3])
{
    float h0[5];
#pragma unroll
    for (int j = 0; j < 5; ++j) {
        const float* w = W0 + (c * 5 + j) * NIN;
        float a = b0[c * 5 + j];
#pragma unroll
        for (int i = 0; i < NIN; ++i) a = fmaf(x[i], w[i], a);
        h0[j] = fmaxf(a, 0.0f);
    }
    float h1[4];
#pragma unroll
    for (int j = 0; j < 4; ++j) {
        const float* w = W1 + (c * 4 + j) * 5;
        float a = b1[c * 4 + j];
#pragma unroll
        for (int i = 0; i < 5; ++i) a = fmaf(h0[i], w[i], a);
        h1[j] = fmaxf(a, 0.0f);
    }
    float h2[4];
#pragma unroll
    for (int j = 0; j < 4; ++j) {
        const float* w = W2 + (c * 4 + j) * 4;
        float a = b2[c * 4 + j];
#pragma unroll
        for (int i = 0; i < 4; ++i) a = fmaf(h1[i], w[i], a);
        h2[j] = fmaxf(a, 0.0f);
    }
    float lg[3];
#pragma unroll
    for (int j = 0; j < 3; ++j) {
        const float* w = W3 + (c * 3 + j) * 4;
        float a = b3[c * 3 + j];
#pragma unroll
        for (int i = 0; i < 4; ++i) a = fmaf(h2[i], w[i], a);
        lg[j] = a;
    }
    float m = fmaxf(fmaxf(lg[0], lg[1]), lg[2]);
    float e0 = __expf(lg[0] - m);
    float e1 = __expf(lg[1] - m);
    float e2 = __expf(lg[2] - m);
    float r = 1.0f / (e0 + e1 + e2);
    o[0] = e0 * r;
    o[1] = e1 * r;
    o[2] = e2 * r;
}

// ---------------------------------------------------------------------------
// Kernel 2: per-channel MLP softmax splits.
// Block = 64 samples x 6 waves; wave w handles channels 7w..7w+6 for its 64
// lanes (lane = sample). Results staged in LDS [64][127] (127 stride: lanes
// writing stride-127 rows hit all 32 banks, 2-way = free), then written out
// block-cooperatively as contiguous, coalesced float2 stores.
// ---------------------------------------------------------------------------
__global__ __launch_bounds__(384) void k_mlp(
    const float* __restrict__ cons,
    const float* __restrict__ mu_direct,
    const float* __restrict__ Wd0, const float* __restrict__ bd0,
    const float* __restrict__ Wf0, const float* __restrict__ bf0,
    const float* __restrict__ Wd1, const float* __restrict__ bd1,
    const float* __restrict__ Wf1, const float* __restrict__ bf1,
    const float* __restrict__ Wd2, const float* __restrict__ bd2,
    const float* __restrict__ Wf2, const float* __restrict__ bf2,
    const float* __restrict__ Wd3, const float* __restrict__ bd3,
    const float* __restrict__ Wf3, const float* __restrict__ bf3,
    float* __restrict__ out, int N)
{
    __shared__ float esd[64 * 127];
    __shared__ float esf[64 * 127];
    const int tid  = threadIdx.x;
    const int lane = tid & 63;
    const int wave = tid >> 6;
    const int n0   = blockIdx.x * 64;
    const int n    = n0 + lane;

    float4 c0 = *(const float4*)(cons + (size_t)n * NCON);
    float4 c1 = *(const float4*)(cons + (size_t)n * NCON + 4);
    float mu  = mu_direct[n];
    float inv = 1.0f / (mu + EPS);
    float xf[8] = {c0.x, c0.y, c0.z, c0.w, c1.x, c1.y, c1.z, c1.w};
    float xd[9];
#pragma unroll
    for (int i = 0; i < 8; ++i) xd[i] = xf[i] * inv;
    xd[8] = mu;

    for (int ci = 0; ci < 7; ++ci) {
        int c = __builtin_amdgcn_readfirstlane(wave * 7 + ci);
        float od[3], og[3];
        mlp_softmax3<9>(xd, c, Wd0, bd0, Wd1, bd1, Wd2, bd2, Wd3, bd3, od);
        mlp_softmax3<8>(xf, c, Wf0, bf0, Wf1, bf1, Wf2, bf2, Wf3, bf3, og);
        int col = c * 3;
#pragma unroll
        for (int k = 0; k < 3; ++k) {
            esd[lane * 127 + col + k] = od[k];
            esf[lane * 127 + col + k] = og[k];
        }
    }
    __syncthreads();

    size_t nctot = (size_t)N * CCH;
    float* gd = out + 2 * nctot + (size_t)n0 * (CCH * 3);
    float* gf = out + 5 * nctot + (size_t)n0 * (CCH * 3);
    // 64 rows x 126 floats = 64*63 float2 per tile, contiguous in global.
    for (int idx = tid; idx < 64 * 63; idx += 384) {
        int r = idx / 63;
        int q = idx - r * 63;
        float2 vd;
        vd.x = esd[r * 127 + 2 * q];
        vd.y = esd[r * 127 + 2 * q + 1];
        float2 vf;
        vf.x = esf[r * 127 + 2 * q];
        vf.y = esf[r * 127 + 2 * q + 1];
        ((float2*)gd)[idx] = vd;
        ((float2*)gf)[idx] = vf;
    }
}

extern "C" void kernel_launch(void* const* d_in, const int* in_sizes, int n_in,
                              void* d_out, int out_size, void* d_ws, size_t ws_size,
                              hipStream_t stream) {
    const float* tau  = (const float*)d_in[0];
    const float* mud  = (const float*)d_in[1];
    const float* muf  = (const float*)d_in[2];
    const float* cons = (const float*)d_in[3];
    // setup_inputs() dict order: Wd{i}, bd{i}, Wf{i}, bf{i} interleaved per layer.
    const float* Wd0 = (const float*)d_in[4];  const float* bd0 = (const float*)d_in[5];
    const float* Wf0 = (const float*)d_in[6];  const float* bf0 = (const float*)d_in[7];
    const float* Wd1 = (const float*)d_in[8];  const float* bd1 = (const float*)d_in[9];
    const float* Wf1 = (const float*)d_in[10]; const float* bf1 = (const float*)d_in[11];
    const float* Wd2 = (const float*)d_in[12]; const float* bd2 = (const float*)d_in[13];
    const float* Wf2 = (const float*)d_in[14]; const float* bf2 = (const float*)d_in[15];
    const float* Wd3 = (const float*)d_in[16]; const float* bd3 = (const float*)d_in[17];
    const float* Wf3 = (const float*)d_in[18]; const float* bf3 = (const float*)d_in[19];
    float* out = (float*)d_out;

    int N = in_sizes[1];          // mu_direct element count = N
    int total = N * CCH;          // N*C
    k_trans<<<(total + 255) / 256, 256, 0, stream>>>(tau, mud, muf, out, total, (size_t)total);
    k_mlp<<<N / 64, 384, 0, stream>>>(cons, mud,
                                      Wd0, bd0, Wf0, bf0,
                                      Wd1, bd1, Wf1, bf1,
                                      Wd2, bd2, Wf2, bf2,
                                      Wd3, bd3, Wf3, bf3,
                                      out, N);
}